// Round 10
// baseline (344.770 us; speedup 1.0000x reference)
//
#include <hip/hip_runtime.h>
#include <hip/hip_bf16.h>

// B=32, N=4096, P=256, L=16, DR=128, H=128, NUM_REL=400.
// Contract (verified r5-r8): float inputs f32, ints int32, output f32 [32][128].
// r9-r17 ladder: MFMA LSTM, rcp activations, lgkm-only barriers, NPB16 TLP
//   (60us), depth-2 x prefetch (55us = best).
// r18 lesson (REVERTED): Whh-in-LDS @1024thr = 169us. 152KB LDS -> ONE
//   barrier domain/CU (16-wave lockstep, r12 lesson at scale) + VGPR 60 ->
//   L2 W-loads serialize in tiny batches. L2-BW theory REFUTED twice:
//   halving W traffic hurt 3x; r13(256KB/CU/step,72us) vs r15(512KB,60us)
//   already showed traffic not binding. r17 structure (2 independent 8-wave
//   domains, W streamed from hot L2 under MFMA) is the right one.
// r19 (this round): r17 + rl-gather software-pipelined ONE STEP AHEAD.
//   r17's remaining serial latency in the recurrence cycle: rl gather sat
//   between MFMA and gates (~200-300cyc L2 exposed/step). Its addresses
//   (s_rid[m][t+1]) are static -> issue the loads in the PREVIOUS step's
//   tail (directly into rlvA, no copy), consume after BAR + MFMA (~700cyc
//   window). r16 failed this by pinning the gather pre-MFMA with a
//   sched_barrier; tail placement avoids interfering with A ds_reads.
//   +16 VGPR live across barrier (108->~124); __launch_bounds__(512,4)
//   forces <=128 so 2 blocks/CU survive. Post-MFMA sched_barrier removed
//   (gates may now interleave with MFMA drain).
//   Tripwires: k_lstm ~70+ = occupancy lost; WRITE_SIZE>5MB = spill.

#define B_    32
#define N_    4096
#define L_    16
#define DR_   128
#define H_    128
#define G4_   512
#define AST2  264        // A row stride in bf16 elems (528B, 16B-aligned)
#define NPATH 8192
#define NPB   16

typedef unsigned short bfraw;
typedef short short8 __attribute__((ext_vector_type(8)));
typedef float f32x4 __attribute__((ext_vector_type(4)));

__device__ int   g_isbf16;
__device__ int   g_isi64;
__device__ __align__(16) bfraw g_Wcat[G4_ * 256];    // [n][k] bf16, 256KB
__device__ __align__(16) float g_relproj[400 * G4_]; // [400][128 units][4 gates] f32
__device__ float g_bias[G4_];
__device__ int   g_perm[NPATH];
__device__ float g_last[NPATH * H_];                 // f32 [8192][128]

// lgkm-only barrier: LDS producer/consumer ordering without the vmcnt(0)
// drain __syncthreads carries. Global loads stay in flight across it.
#define BAR() asm volatile("s_waitcnt lgkmcnt(0)\n\ts_barrier" ::: "memory")

__device__ __forceinline__ float bfc(bfraw v) {
    return __uint_as_float(((unsigned)v) << 16);
}
__device__ __forceinline__ bfraw f2b(float f) {      // RNE f32->bf16
    unsigned u = __float_as_uint(f);
    return (bfraw)((u + 0x7FFFu + ((u >> 16) & 1u)) >> 16);
}
__device__ __forceinline__ unsigned pk2(float a, float b) {
    return (unsigned)f2b(a) | ((unsigned)f2b(b) << 16);
}
__device__ __forceinline__ float ld(const void* p, size_t i, int isbf) {
    return isbf ? bfc(((const bfraw*)p)[i]) : ((const float*)p)[i];
}
// v_rcp_f32-based activations (confirmed r11: VALUBusy 29->20%).
__device__ __forceinline__ float sigf(float x) {
    return __builtin_amdgcn_rcpf(1.0f + __expf(-x));
}
__device__ __forceinline__ float tanhfast(float x) {
    return 2.0f * sigf(2.0f * x) - 1.0f;
}

// dot of 128 contiguous f32 (global w) with 128 f32 in LDS
__device__ __forceinline__ float dot128(const float* __restrict__ w,
                                        const float* __restrict__ s) {
    float acc = 0.f;
    #pragma unroll
    for (int i = 0; i < 32; ++i) {
        const float4 wv = *(const float4*)(w + i * 4);
        acc = fmaf(wv.x, s[i*4+0], fmaf(wv.y, s[i*4+1],
              fmaf(wv.z, s[i*4+2], fmaf(wv.w, s[i*4+3], acc))));
    }
    return acc;
}

// ---------------------------------------------------------------------------
// Fused prep (unchanged), grid 657 x 512 threads.
__global__ __launch_bounds__(512) void k_prep(
    const void* __restrict__ node_opt, const int* __restrict__ node_idx,
    const void* __restrict__ rel_embeds,
    const void* __restrict__ W_ih, const void* __restrict__ W_hh,
    const void* __restrict__ b_ih, const void* __restrict__ b_hh,
    const int* __restrict__ path_lens)
{
    __shared__ float relv[DR_];
    __shared__ int s_big, s_nz, hist[16], cur[16];
    const int tid = threadIdx.x;
    const int blk = blockIdx.x;

    if (tid == 0) { s_big = 0; s_nz = 0; }
    __syncthreads();
    {
        const unsigned short* u = (const unsigned short*)node_opt;
        int big = 0;
        #pragma unroll
        for (int i = 0; i < 4; ++i) {
            const float v = fabsf(bfc(u[tid + i * 512]));
            big |= !(v < 1.0e3f);             // NaN-safe
        }
        if (big) s_big = 1;
        if (node_idx[2 * tid + 1] != 0) s_nz = 1;   // int width probe
    }
    __syncthreads();
    const int isbf = s_big ? 0 : 1;
    const int i64  = s_nz ? 0 : 1;

    if (blk < 400) {
        const int r = blk;
        if (tid < DR_) relv[tid] = ld(rel_embeds, (size_t)r * DR_ + tid, isbf);
        __syncthreads();
        const int n = tid;                     // 0..511, n = g*128+u
        float s;
        if (isbf) {
            s = 0.f;
            for (int d = 0; d < DR_; ++d)
                s = fmaf(relv[d], bfc(((const bfraw*)W_ih)[(size_t)n * 256 + 128 + d]), s);
        } else {
            s = dot128((const float*)W_ih + (size_t)n * 256 + 128, relv);
        }
        g_relproj[r * G4_ + ((n & 127) << 2) + (n >> 7)] = s;
    } else if (blk < 656) {
        const int idx = (blk - 400) * 512 + tid;   // 0..131071
        const int n = idx >> 8, k = idx & 255;
        const float v = (k < H_) ? ld(W_hh, (size_t)n * H_ + k, isbf)
                                 : ld(W_ih, (size_t)n * 256 + (k - H_), isbf);
        g_Wcat[n * 256 + k] = f2b(v);
    } else {
        if (tid == 0) { g_isbf16 = isbf; g_isi64 = i64; }
        g_bias[tid] = ld(b_ih, tid, isbf) + ld(b_hh, tid, isbf);
        if (tid < 16) hist[tid] = 0;
        __syncthreads();
        for (int p = tid; p < NPATH; p += 512) {
            const int len = i64 ? path_lens[2 * p] : path_lens[p];
            atomicAdd(&hist[len - 1], 1);
        }
        __syncthreads();
        if (tid == 0) {
            int off = 0;
            for (int b = 15; b >= 0; --b) { cur[b] = off; off += hist[b]; }
        }
        __syncthreads();
        for (int p = tid; p < NPATH; p += 512) {
            const int len = i64 ? path_lens[2 * p] : path_lens[p];
            const int pos = atomicAdd(&cur[len - 1], 1);
            g_perm[pos] = p;
        }
    }
}

// ---------------------------------------------------------------------------
// MFMA LSTM: 512 blocks x 512 threads (8 waves), 16 paths/block, N=512, K=256.
// 2 blocks/CU (forced by launch_bounds(512,4) VGPR cap). Double-buffered A,
// one barrier per step. Depth-2 x prefetch + one-step-ahead rl prefetch:
//   issue x(t+2)->pnB -> 8 ds_read_b128(A[cur]) + 32 MFMA ->
//   gates (rlvA loaded LAST step, pnA committed) -> reload rlvA for t+1 -> BAR.
__global__ __launch_bounds__(512, 4) void k_lstm(
    const void* __restrict__ graph_embed,   // [32][4096][128] f32 (or bf16)
    const int*  __restrict__ node_idx,      // [8192][16]
    const int*  __restrict__ rel_idx,       // [8192][16]
    const int*  __restrict__ path_lens)     // [8192]
{
    __shared__ __align__(16) bfraw Abuf[2][NPB][AST2]; // [buf][path][ h | x ]
    __shared__ int s_pid[NPB], s_len[NPB];
    __shared__ int s_nid[NPB][L_], s_rid[NPB][L_];

    const int isbf = g_isbf16;
    const int i64  = g_isi64;
    const int tid  = threadIdx.x;

    if (tid < NPB) {
        const int pid = g_perm[blockIdx.x * NPB + tid];
        s_pid[tid] = pid;
        s_len[tid] = i64 ? path_lens[2 * pid] : path_lens[pid];
    }
    __syncthreads();
    if (tid < 256) {   // indices: 256 threads = 16 paths x 16 steps
        const int m = tid >> 4, t = tid & 15;
        const int idx = s_pid[m] * L_ + t;
        s_nid[m][t] = i64 ? node_idx[2 * idx] : node_idx[idx];
        s_rid[m][t] = i64 ? rel_idx[2 * idx]  : rel_idx[idx];
    }
    if (tid < 256) {   // zero h region of buffer 0 (k<128): 16 rows x 128 bf16
        const int m = tid >> 4, i0 = (tid & 15) * 8;
        *(uint4*)&Abuf[0][m][i0] = make_uint4(0, 0, 0, 0);
    }
    __syncthreads();

    int maxlen = 0;
    #pragma unroll
    for (int m = 0; m < NPB; ++m) maxlen = max(maxlen, s_len[m]);

    const int w    = tid >> 6;     // wave 0..7
    const int l    = tid & 63;
    const int quad = l >> 4;
    const int col  = l & 15;
    const int u0   = w * 16 + col; // owned unit

    // ---- resident W fragments: wreg[ck][g] = W[g*128+u0][ck*32+quad*8 ..+8] ----
    short8 wreg[8][4];
    float bq4[4];
    #pragma unroll
    for (int g = 0; g < 4; ++g) {
        bq4[g] = g_bias[g * 128 + u0];
        const bfraw* wrow = g_Wcat + (size_t)(g * 128 + u0) * 256 + quad * 8;
        #pragma unroll
        for (int ck = 0; ck < 8; ++ck)
            wreg[ck][g] = *(const short8*)(wrow + ck * 32);
    }

    // x-gather geometry: 32 threads/path, 4 elems (pi0) each.
    const int pm  = tid >> 5;          // path 0..15
    const int pi0 = (tid & 31) * 4;    // elem 0..124
    const size_t gbase = (size_t)(s_pid[pm] >> 8) * (size_t)(N_ * DR_);

    uint4 pnA, pnB;   // depth-2 x prefetch regs (f32: 4 floats; bf16: .x/.y)

    // ---- prologue: load + commit x(0) into buffer 0 (t=0 < len always) ----
    {
        const int nid = s_nid[pm][0];
        uint2 npk;
        if (isbf) {
            npk = *(const uint2*)((const bfraw*)graph_embed + gbase + (size_t)nid * DR_ + pi0);
        } else {
            const float* gp = (const float*)graph_embed + gbase + (size_t)nid * DR_ + pi0;
            const uint4 q = *(const uint4*)gp;
            const float* a = (const float*)&q;
            npk = make_uint2(pk2(a[0], a[1]), pk2(a[2], a[3]));
        }
        *(uint2*)&Abuf[0][pm][128 + pi0] = npk;
    }
    // issue x(1) -> pnA (committed at end of step 0)
    if (maxlen > 1) {
        const int nid = s_nid[pm][1];
        if (isbf) {
            const uint2 q = *(const uint2*)((const bfraw*)graph_embed + gbase + (size_t)nid * DR_ + pi0);
            pnA.x = q.x; pnA.y = q.y;
        } else {
            pnA = *(const uint4*)((const float*)graph_embed + gbase + (size_t)nid * DR_ + pi0);
        }
    }
    // issue rl(0) -> rlvA (consumed in step 0's gates, after MFMA)
    f32x4 rlvA[4];
    #pragma unroll
    for (int r = 0; r < 4; ++r) {
        const int m = quad * 4 + r;
        rlvA[r] = *(const f32x4*)(g_relproj + (size_t)s_rid[m][0] * G4_ + u0 * 4);
    }
    __syncthreads();                       // x(0) + h(-1)=0 visible

    float c[4];
    #pragma unroll
    for (int r = 0; r < 4; ++r) c[r] = 0.f;

    bfraw (*Ar)[AST2] = Abuf[0];   // read buffer  (h(t-1), x(t))
    bfraw (*Aw)[AST2] = Abuf[1];   // write buffer (h(t), x(t+1))

    for (int t = 0; t < maxlen; ++t) {
        const bool more = (t + 1 < maxlen);   // block-uniform

        // [A] issue x(t+2) -> pnB (window ~2 steps covers miss latency).
        if (t + 2 < maxlen) {
            const int nid = s_nid[pm][t + 2];
            if (isbf) {
                const uint2 q = *(const uint2*)((const bfraw*)graph_embed + gbase + (size_t)nid * DR_ + pi0);
                pnB.x = q.x; pnB.y = q.y;
            } else {
                pnB = *(const uint4*)((const float*)graph_embed + gbase + (size_t)nid * DR_ + pi0);
            }
        }

        // [B] MFMA K-loop: A[cur] from LDS, W from registers (M=16 tile)
        f32x4 acc[4];
        #pragma unroll
        for (int g = 0; g < 4; ++g) {
            const float b = bq4[g];
            acc[g][0] = b; acc[g][1] = b; acc[g][2] = b; acc[g][3] = b;
        }
        #pragma unroll
        for (int ck = 0; ck < 8; ++ck) {
            const short8 a0 = *(const short8*)&Ar[col][ck * 32 + quad * 8];
            #pragma unroll
            for (int g = 0; g < 4; ++g)
                acc[g] = __builtin_amdgcn_mfma_f32_16x16x32_bf16(a0, wreg[ck][g], acc[g], 0, 0, 0);
        }
        // (no sched fence: gates may interleave with MFMA drain; rl loads
        // for this step were issued LAST step, so nothing to pin here.)

        // [C] gates + cell update; rlvA was loaded one step ago (latency
        // covered by barrier + MFMA). h(t) goes to the WRITE buffer.
        #pragma unroll
        for (int r = 0; r < 4; ++r) {
            const int m = quad * 4 + r;
            const float relm = (t < s_len[m] - 1) ? 1.0f : 0.0f;
            const float ig = sigf(acc[0][r] + relm * rlvA[r][0]);
            const float fg = sigf(acc[1][r] + relm * rlvA[r][1]);
            const float gg = tanhfast(acc[2][r] + relm * rlvA[r][2]);
            const float og = sigf(acc[3][r] + relm * rlvA[r][3]);
            const float cc = fg * c[r] + ig * gg;
            c[r] = cc;
            const float h = og * tanhfast(cc);
            Aw[m][u0] = f2b(h);
            if (t == s_len[m] - 1)
                g_last[(size_t)s_pid[m] * H_ + u0] = h;
        }

        // [D] commit pnA = x(t+1) into the WRITE buffer (masked per-path);
        // rotate the x prefetch pipe.
        if (more) {
            uint2 npk = make_uint2(0, 0);
            if (t + 1 < s_len[pm]) {
                if (isbf) npk = make_uint2(pnA.x, pnA.y);
                else {
                    const float* a = (const float*)&pnA;
                    npk = make_uint2(pk2(a[0], a[1]), pk2(a[2], a[3]));
                }
            }
            *(uint2*)&Aw[pm][128 + pi0] = npk;
            pnA = pnB;
        }

        // [E] issue rl(t+1) directly into rlvA (old value dead after gates).
        // In flight across BAR + next MFMA cluster (~700cyc window).
        if (more) {
            #pragma unroll
            for (int r = 0; r < 4; ++r) {
                const int m = quad * 4 + r;
                rlvA[r] = *(const f32x4*)(g_relproj + (size_t)s_rid[m][t + 1] * G4_ + u0 * 4);
            }
        }

        // [F] single barrier: my A[cur] reads retired (own lgkm drain); all
        // waves' A[nxt] writes visible for step t+1. Buffers swap roles.
        BAR();
        bfraw (*tmp)[AST2] = Ar; Ar = Aw; Aw = tmp;
    }
}

// ---------------------------------------------------------------------------
// Attention epilogue, one block per batch element (r16 ILP variant).
__global__ __launch_bounds__(256) void k_attn(
    const void* __restrict__ node_opt,    // [32][128]
    const void* __restrict__ in_proj_w,   // [384][128]
    const void* __restrict__ in_proj_b,   // [384]
    const void* __restrict__ out_proj_w,  // [128][128]
    const void* __restrict__ out_proj_b,  // [128]
    float* __restrict__ out)              // [32][128] f32
{
    const int isbf = g_isbf16;
    const int b = blockIdx.x, tid = threadIdx.x;
    __shared__ __align__(16) float s_no[128], q[128], qk[128], sv2[2][128], ctx[128];
    __shared__ float logits[256];
    __shared__ float red[12];

    const int u    = tid & 127;      // output index for split phases
    const int half = tid >> 7;       // 0/1: j-range half

    if (tid < 128) s_no[tid] = ld(node_opt, b * 128 + tid, isbf);
    __syncthreads();
    {   // q[u] = node_opt . Wq[u] + bq  (2 threads per output, 64 j each)
        float s = 0.f;
        const int j0 = half * 64;
        if (isbf) {
            #pragma unroll 8
            for (int j = 0; j < 64; ++j)
                s = fmaf(s_no[j0 + j], ld(in_proj_w, (size_t)u * 128 + j0 + j, 1), s);
        } else {
            const float* wr = (const float*)in_proj_w + (size_t)u * 128 + j0;
            #pragma unroll
            for (int i = 0; i < 16; ++i) {
                const float4 wv = *(const float4*)(wr + i * 4);
                s = fmaf(wv.x, s_no[j0+i*4+0], fmaf(wv.y, s_no[j0+i*4+1],
                    fmaf(wv.z, s_no[j0+i*4+2], fmaf(wv.w, s_no[j0+i*4+3], s))));
            }
        }
        sv2[half][u] = s;
    }
    __syncthreads();
    if (tid < 128) q[tid] = sv2[0][tid] + sv2[1][tid] + ld(in_proj_b, tid, isbf);
    __syncthreads();
    {   // qk[u] = sum_j q[j] * Wk[j][u]  (2 threads per output, 64 j each)
        float s = 0.f;
        const int j0 = half * 64;
        #pragma unroll 8
        for (int j = 0; j < 64; ++j)
            s = fmaf(q[j0 + j], ld(in_proj_w, (size_t)(128 + j0 + j) * 128 + u, isbf), s);
        sv2[half][u] = s;
    }
    if (tid == 0) {     // q . bk
        float s = 0.f;
        #pragma unroll 8
        for (int j = 0; j < 128; ++j)
            s = fmaf(q[j], ld(in_proj_b, 128 + j, isbf), s);
        red[10] = s;
    }
    __syncthreads();
    if (tid < 128) qk[tid] = sv2[0][tid] + sv2[1][tid];
    __syncthreads();
    {   // logit for path p = tid
        const float* lp = g_last + ((size_t)b * 256 + tid) * H_;
        const float s = dot128(lp, qk);
        logits[tid] = (s + red[10]) * 0.08838834764831845f;  // 1/sqrt(128)
    }
    __syncthreads();
    float v = logits[tid];
    #pragma unroll
    for (int off = 32; off > 0; off >>= 1) v = fmaxf(v, __shfl_xor(v, off, 64));
    if ((tid & 63) == 0) red[tid >> 6] = v;
    __syncthreads();
    if (tid == 0) red[8] = fmaxf(fmaxf(red[0], red[1]), fmaxf(red[2], red[3]));
    __syncthreads();
    const float e = __expf(logits[tid] - red[8]);
    float sum = e;
    #pragma unroll
    for (int off = 32; off > 0; off >>= 1) sum += __shfl_xor(sum, off, 64);
    if ((tid & 63) == 0) red[4 + (tid >> 6)] = sum;
    __syncthreads();
    if (tid == 0) red[9] = red[4] + red[5] + red[6] + red[7];
    __syncthreads();
    logits[tid] = e / red[9];
    __syncthreads();
    {   // sv[u] = sum_p attn[p] * last[b,p,u]  (2 threads per output)
        float s = 0.f;
        const float* lb = g_last + ((size_t)b * 256 + half * 128) * H_ + u;
        #pragma unroll 8
        for (int p = 0; p < 128; ++p)
            s = fmaf(logits[half * 128 + p], lb[(size_t)p * H_], s);
        sv2[half][u] = s;
    }
    __syncthreads();
    if (tid < 128) q[tid] = sv2[0][tid] + sv2[1][tid];   // reuse q[] as sv
    __syncthreads();
    if (tid < 128) {
        float s;
        if (isbf) {
            s = 0.f;
            #pragma unroll 8
            for (int j = 0; j < 128; ++j)
                s = fmaf(q[j], ld(in_proj_w, (size_t)(256 + tid) * 128 + j, 1), s);
        } else {
            s = dot128((const float*)in_proj_w + (size_t)(256 + tid) * 128, q);
        }
        ctx[tid] = s + ld(in_proj_b, 256 + tid, isbf);
    }
    __syncthreads();
    if (tid < 128) {
        float s;
        if (isbf) {
            s = 0.f;
            #pragma unroll 8
            for (int d = 0; d < 128; ++d)
                s = fmaf(ctx[d], ld(out_proj_w, (size_t)tid * 128 + d, 1), s);
        } else {
            s = dot128((const float*)out_proj_w + (size_t)tid * 128, ctx);
        }
        out[b * 128 + tid] = s + ld(out_proj_b, tid, isbf);
    }
}

// ---------------------------------------------------------------------------
extern "C" void kernel_launch(void* const* d_in, const int* in_sizes, int n_in,
                              void* d_out, int out_size, void* d_ws, size_t ws_size,
                              hipStream_t stream)
{
    const void* graph_embed = d_in[0];
    const void* node_opt    = d_in[1];
    const void* rel_embeds  = d_in[2];
    const void* W_ih        = d_in[3];
    const void* W_hh        = d_in[4];
    const void* b_ih        = d_in[5];
    const void* b_hh        = d_in[6];
    const void* in_proj_w   = d_in[7];
    const void* in_proj_b   = d_in[8];
    const void* out_proj_w  = d_in[9];
    const void* out_proj_b  = d_in[10];
    const int* node_idx  = (const int*)d_in[11];
    const int* rel_idx   = (const int*)d_in[12];
    const int* path_lens = (const int*)d_in[13];
    (void)d_ws; (void)ws_size; (void)in_sizes; (void)n_in; (void)out_size;

    hipLaunchKernelGGL(k_prep, dim3(657), dim3(512), 0, stream,
                       node_opt, node_idx, rel_embeds, W_ih, W_hh, b_ih, b_hh,
                       path_lens);
    hipLaunchKernelGGL(k_lstm, dim3(NPATH / NPB), dim3(512), 0, stream,
                       graph_embed, node_idx, rel_idx, path_lens);
    hipLaunchKernelGGL(k_attn, dim3(B_), dim3(256), 0, stream,
                       node_opt, in_proj_w, in_proj_b, out_proj_w, out_proj_b,
                       (float*)d_out);
}

// Round 11
// 202.675 us; speedup vs baseline: 1.7011x; 1.7011x over previous
//
#include <hip/hip_runtime.h>
#include <hip/hip_bf16.h>

// B=32, N=4096, P=256, L=16, DR=128, H=128, NUM_REL=400.
// Contract (verified r5-r8): float inputs f32, ints int32, output f32 [32][128].
// r9-r17 ladder: MFMA LSTM, rcp activations, lgkm-only barriers, NPB16 TLP
//   (60us), depth-2 x prefetch (55us = best).
// r18 lesson: Whh-in-LDS @1024thr = 169us (one barrier domain + VGPR 60).
// r19 lesson (REVERTED): __launch_bounds__(512,4) crushed allocator to 64
//   VGPR -> everything spilled (FETCH 372MB, WRITE 94MB, 193us). The
//   rl-ahead schedule was never actually tested — experiment confounded.
// r20 (this round): clean test of rl-ahead with r17's proven bounds (512,2).
//   rl gather issued in the step TAIL (post-gates, pre-BAR) directly into
//   rlvA; consumed after BAR + next MFMA cluster (~700cyc window vs ~250cyc
//   exposed in r17). Natural allocation ~124 VGPR (108 + 16 rlvA across
//   barrier) <= 128 keeps 4 waves/SIMD = 2 blocks/CU (m69 table).
//   Tripwires: Occupancy ~13% = lost a block/CU -> revert to r17;
//   WRITE_SIZE > 5MB = spill -> revert; null result = rl gather exonerated.

#define B_    32
#define N_    4096
#define L_    16
#define DR_   128
#define H_    128
#define G4_   512
#define AST2  264        // A row stride in bf16 elems (528B, 16B-aligned)
#define NPATH 8192
#define NPB   16

typedef unsigned short bfraw;
typedef short short8 __attribute__((ext_vector_type(8)));
typedef float f32x4 __attribute__((ext_vector_type(4)));

__device__ int   g_isbf16;
__device__ int   g_isi64;
__device__ __align__(16) bfraw g_Wcat[G4_ * 256];    // [n][k] bf16, 256KB
__device__ __align__(16) float g_relproj[400 * G4_]; // [400][128 units][4 gates] f32
__device__ float g_bias[G4_];
__device__ int   g_perm[NPATH];
__device__ float g_last[NPATH * H_];                 // f32 [8192][128]

// lgkm-only barrier: LDS producer/consumer ordering without the vmcnt(0)
// drain __syncthreads carries. Global loads stay in flight across it.
#define BAR() asm volatile("s_waitcnt lgkmcnt(0)\n\ts_barrier" ::: "memory")

__device__ __forceinline__ float bfc(bfraw v) {
    return __uint_as_float(((unsigned)v) << 16);
}
__device__ __forceinline__ bfraw f2b(float f) {      // RNE f32->bf16
    unsigned u = __float_as_uint(f);
    return (bfraw)((u + 0x7FFFu + ((u >> 16) & 1u)) >> 16);
}
__device__ __forceinline__ unsigned pk2(float a, float b) {
    return (unsigned)f2b(a) | ((unsigned)f2b(b) << 16);
}
__device__ __forceinline__ float ld(const void* p, size_t i, int isbf) {
    return isbf ? bfc(((const bfraw*)p)[i]) : ((const float*)p)[i];
}
// v_rcp_f32-based activations (confirmed r11: VALUBusy 29->20%).
__device__ __forceinline__ float sigf(float x) {
    return __builtin_amdgcn_rcpf(1.0f + __expf(-x));
}
__device__ __forceinline__ float tanhfast(float x) {
    return 2.0f * sigf(2.0f * x) - 1.0f;
}

// dot of 128 contiguous f32 (global w) with 128 f32 in LDS
__device__ __forceinline__ float dot128(const float* __restrict__ w,
                                        const float* __restrict__ s) {
    float acc = 0.f;
    #pragma unroll
    for (int i = 0; i < 32; ++i) {
        const float4 wv = *(const float4*)(w + i * 4);
        acc = fmaf(wv.x, s[i*4+0], fmaf(wv.y, s[i*4+1],
              fmaf(wv.z, s[i*4+2], fmaf(wv.w, s[i*4+3], acc))));
    }
    return acc;
}

// ---------------------------------------------------------------------------
// Fused prep (unchanged), grid 657 x 512 threads.
__global__ __launch_bounds__(512) void k_prep(
    const void* __restrict__ node_opt, const int* __restrict__ node_idx,
    const void* __restrict__ rel_embeds,
    const void* __restrict__ W_ih, const void* __restrict__ W_hh,
    const void* __restrict__ b_ih, const void* __restrict__ b_hh,
    const int* __restrict__ path_lens)
{
    __shared__ float relv[DR_];
    __shared__ int s_big, s_nz, hist[16], cur[16];
    const int tid = threadIdx.x;
    const int blk = blockIdx.x;

    if (tid == 0) { s_big = 0; s_nz = 0; }
    __syncthreads();
    {
        const unsigned short* u = (const unsigned short*)node_opt;
        int big = 0;
        #pragma unroll
        for (int i = 0; i < 4; ++i) {
            const float v = fabsf(bfc(u[tid + i * 512]));
            big |= !(v < 1.0e3f);             // NaN-safe
        }
        if (big) s_big = 1;
        if (node_idx[2 * tid + 1] != 0) s_nz = 1;   // int width probe
    }
    __syncthreads();
    const int isbf = s_big ? 0 : 1;
    const int i64  = s_nz ? 0 : 1;

    if (blk < 400) {
        const int r = blk;
        if (tid < DR_) relv[tid] = ld(rel_embeds, (size_t)r * DR_ + tid, isbf);
        __syncthreads();
        const int n = tid;                     // 0..511, n = g*128+u
        float s;
        if (isbf) {
            s = 0.f;
            for (int d = 0; d < DR_; ++d)
                s = fmaf(relv[d], bfc(((const bfraw*)W_ih)[(size_t)n * 256 + 128 + d]), s);
        } else {
            s = dot128((const float*)W_ih + (size_t)n * 256 + 128, relv);
        }
        g_relproj[r * G4_ + ((n & 127) << 2) + (n >> 7)] = s;
    } else if (blk < 656) {
        const int idx = (blk - 400) * 512 + tid;   // 0..131071
        const int n = idx >> 8, k = idx & 255;
        const float v = (k < H_) ? ld(W_hh, (size_t)n * H_ + k, isbf)
                                 : ld(W_ih, (size_t)n * 256 + (k - H_), isbf);
        g_Wcat[n * 256 + k] = f2b(v);
    } else {
        if (tid == 0) { g_isbf16 = isbf; g_isi64 = i64; }
        g_bias[tid] = ld(b_ih, tid, isbf) + ld(b_hh, tid, isbf);
        if (tid < 16) hist[tid] = 0;
        __syncthreads();
        for (int p = tid; p < NPATH; p += 512) {
            const int len = i64 ? path_lens[2 * p] : path_lens[p];
            atomicAdd(&hist[len - 1], 1);
        }
        __syncthreads();
        if (tid == 0) {
            int off = 0;
            for (int b = 15; b >= 0; --b) { cur[b] = off; off += hist[b]; }
        }
        __syncthreads();
        for (int p = tid; p < NPATH; p += 512) {
            const int len = i64 ? path_lens[2 * p] : path_lens[p];
            const int pos = atomicAdd(&cur[len - 1], 1);
            g_perm[pos] = p;
        }
    }
}

// ---------------------------------------------------------------------------
// MFMA LSTM: 512 blocks x 512 threads (8 waves), 16 paths/block, N=512, K=256.
// 2 blocks/CU (natural allocation, r17-proven bounds). Double-buffered A,
// one barrier per step. Depth-2 x prefetch + one-step-ahead rl prefetch:
//   issue x(t+2)->pnB -> 8 ds_read_b128(A[cur]) + 32 MFMA ->
//   gates (rlvA loaded LAST step) -> commit pnA -> reload rlvA for t+1 -> BAR.
__global__ __launch_bounds__(512, 2) void k_lstm(
    const void* __restrict__ graph_embed,   // [32][4096][128] f32 (or bf16)
    const int*  __restrict__ node_idx,      // [8192][16]
    const int*  __restrict__ rel_idx,       // [8192][16]
    const int*  __restrict__ path_lens)     // [8192]
{
    __shared__ __align__(16) bfraw Abuf[2][NPB][AST2]; // [buf][path][ h | x ]
    __shared__ int s_pid[NPB], s_len[NPB];
    __shared__ int s_nid[NPB][L_], s_rid[NPB][L_];

    const int isbf = g_isbf16;
    const int i64  = g_isi64;
    const int tid  = threadIdx.x;

    if (tid < NPB) {
        const int pid = g_perm[blockIdx.x * NPB + tid];
        s_pid[tid] = pid;
        s_len[tid] = i64 ? path_lens[2 * pid] : path_lens[pid];
    }
    __syncthreads();
    if (tid < 256) {   // indices: 256 threads = 16 paths x 16 steps
        const int m = tid >> 4, t = tid & 15;
        const int idx = s_pid[m] * L_ + t;
        s_nid[m][t] = i64 ? node_idx[2 * idx] : node_idx[idx];
        s_rid[m][t] = i64 ? rel_idx[2 * idx]  : rel_idx[idx];
    }
    if (tid < 256) {   // zero h region of buffer 0 (k<128): 16 rows x 128 bf16
        const int m = tid >> 4, i0 = (tid & 15) * 8;
        *(uint4*)&Abuf[0][m][i0] = make_uint4(0, 0, 0, 0);
    }
    __syncthreads();

    int maxlen = 0;
    #pragma unroll
    for (int m = 0; m < NPB; ++m) maxlen = max(maxlen, s_len[m]);

    const int w    = tid >> 6;     // wave 0..7
    const int l    = tid & 63;
    const int quad = l >> 4;
    const int col  = l & 15;
    const int u0   = w * 16 + col; // owned unit

    // ---- resident W fragments: wreg[ck][g] = W[g*128+u0][ck*32+quad*8 ..+8] ----
    short8 wreg[8][4];
    float bq4[4];
    #pragma unroll
    for (int g = 0; g < 4; ++g) {
        bq4[g] = g_bias[g * 128 + u0];
        const bfraw* wrow = g_Wcat + (size_t)(g * 128 + u0) * 256 + quad * 8;
        #pragma unroll
        for (int ck = 0; ck < 8; ++ck)
            wreg[ck][g] = *(const short8*)(wrow + ck * 32);
    }

    // x-gather geometry: 32 threads/path, 4 elems (pi0) each.
    const int pm  = tid >> 5;          // path 0..15
    const int pi0 = (tid & 31) * 4;    // elem 0..124
    const size_t gbase = (size_t)(s_pid[pm] >> 8) * (size_t)(N_ * DR_);

    uint4 pnA, pnB;   // depth-2 x prefetch regs (f32: 4 floats; bf16: .x/.y)

    // ---- prologue: load + commit x(0) into buffer 0 (t=0 < len always) ----
    {
        const int nid = s_nid[pm][0];
        uint2 npk;
        if (isbf) {
            npk = *(const uint2*)((const bfraw*)graph_embed + gbase + (size_t)nid * DR_ + pi0);
        } else {
            const float* gp = (const float*)graph_embed + gbase + (size_t)nid * DR_ + pi0;
            const uint4 q = *(const uint4*)gp;
            const float* a = (const float*)&q;
            npk = make_uint2(pk2(a[0], a[1]), pk2(a[2], a[3]));
        }
        *(uint2*)&Abuf[0][pm][128 + pi0] = npk;
    }
    // issue x(1) -> pnA (committed at end of step 0)
    if (maxlen > 1) {
        const int nid = s_nid[pm][1];
        if (isbf) {
            const uint2 q = *(const uint2*)((const bfraw*)graph_embed + gbase + (size_t)nid * DR_ + pi0);
            pnA.x = q.x; pnA.y = q.y;
        } else {
            pnA = *(const uint4*)((const float*)graph_embed + gbase + (size_t)nid * DR_ + pi0);
        }
    }
    // issue rl(0) -> rlvA (consumed in step 0's gates, after MFMA)
    f32x4 rlvA[4];
    #pragma unroll
    for (int r = 0; r < 4; ++r) {
        const int m = quad * 4 + r;
        rlvA[r] = *(const f32x4*)(g_relproj + (size_t)s_rid[m][0] * G4_ + u0 * 4);
    }
    __syncthreads();                       // x(0) + h(-1)=0 visible

    float c[4];
    #pragma unroll
    for (int r = 0; r < 4; ++r) c[r] = 0.f;

    bfraw (*Ar)[AST2] = Abuf[0];   // read buffer  (h(t-1), x(t))
    bfraw (*Aw)[AST2] = Abuf[1];   // write buffer (h(t), x(t+1))

    for (int t = 0; t < maxlen; ++t) {
        const bool more = (t + 1 < maxlen);   // block-uniform

        // [A] issue x(t+2) -> pnB (window ~2 steps covers miss latency).
        if (t + 2 < maxlen) {
            const int nid = s_nid[pm][t + 2];
            if (isbf) {
                const uint2 q = *(const uint2*)((const bfraw*)graph_embed + gbase + (size_t)nid * DR_ + pi0);
                pnB.x = q.x; pnB.y = q.y;
            } else {
                pnB = *(const uint4*)((const float*)graph_embed + gbase + (size_t)nid * DR_ + pi0);
            }
        }

        // [B] MFMA K-loop: A[cur] from LDS, W from registers (M=16 tile)
        f32x4 acc[4];
        #pragma unroll
        for (int g = 0; g < 4; ++g) {
            const float b = bq4[g];
            acc[g][0] = b; acc[g][1] = b; acc[g][2] = b; acc[g][3] = b;
        }
        #pragma unroll
        for (int ck = 0; ck < 8; ++ck) {
            const short8 a0 = *(const short8*)&Ar[col][ck * 32 + quad * 8];
            #pragma unroll
            for (int g = 0; g < 4; ++g)
                acc[g] = __builtin_amdgcn_mfma_f32_16x16x32_bf16(a0, wreg[ck][g], acc[g], 0, 0, 0);
        }
        // (no sched fence: gates may interleave with MFMA drain; rl loads
        // for this step were issued LAST step, so nothing to pin here.)

        // [C] gates + cell update; rlvA was loaded one step ago (latency
        // covered by barrier + MFMA). h(t) goes to the WRITE buffer.
        #pragma unroll
        for (int r = 0; r < 4; ++r) {
            const int m = quad * 4 + r;
            const float relm = (t < s_len[m] - 1) ? 1.0f : 0.0f;
            const float ig = sigf(acc[0][r] + relm * rlvA[r][0]);
            const float fg = sigf(acc[1][r] + relm * rlvA[r][1]);
            const float gg = tanhfast(acc[2][r] + relm * rlvA[r][2]);
            const float og = sigf(acc[3][r] + relm * rlvA[r][3]);
            const float cc = fg * c[r] + ig * gg;
            c[r] = cc;
            const float h = og * tanhfast(cc);
            Aw[m][u0] = f2b(h);
            if (t == s_len[m] - 1)
                g_last[(size_t)s_pid[m] * H_ + u0] = h;
        }

        // [D] commit pnA = x(t+1) into the WRITE buffer (masked per-path);
        // rotate the x prefetch pipe.
        if (more) {
            uint2 npk = make_uint2(0, 0);
            if (t + 1 < s_len[pm]) {
                if (isbf) npk = make_uint2(pnA.x, pnA.y);
                else {
                    const float* a = (const float*)&pnA;
                    npk = make_uint2(pk2(a[0], a[1]), pk2(a[2], a[3]));
                }
            }
            *(uint2*)&Aw[pm][128 + pi0] = npk;
            pnA = pnB;
        }

        // [E] issue rl(t+1) directly into rlvA (old value dead after gates).
        // In flight across BAR + next MFMA cluster (~700cyc window).
        if (more) {
            #pragma unroll
            for (int r = 0; r < 4; ++r) {
                const int m = quad * 4 + r;
                rlvA[r] = *(const f32x4*)(g_relproj + (size_t)s_rid[m][t + 1] * G4_ + u0 * 4);
            }
        }

        // [F] single barrier: my A[cur] reads retired (own lgkm drain); all
        // waves' A[nxt] writes visible for step t+1. Buffers swap roles.
        BAR();
        bfraw (*tmp)[AST2] = Ar; Ar = Aw; Aw = tmp;
    }
}

// ---------------------------------------------------------------------------
// Attention epilogue, one block per batch element (r16 ILP variant).
__global__ __launch_bounds__(256) void k_attn(
    const void* __restrict__ node_opt,    // [32][128]
    const void* __restrict__ in_proj_w,   // [384][128]
    const void* __restrict__ in_proj_b,   // [384]
    const void* __restrict__ out_proj_w,  // [128][128]
    const void* __restrict__ out_proj_b,  // [128]
    float* __restrict__ out)              // [32][128] f32
{
    const int isbf = g_isbf16;
    const int b = blockIdx.x, tid = threadIdx.x;
    __shared__ __align__(16) float s_no[128], q[128], qk[128], sv2[2][128], ctx[128];
    __shared__ float logits[256];
    __shared__ float red[12];

    const int u    = tid & 127;      // output index for split phases
    const int half = tid >> 7;       // 0/1: j-range half

    if (tid < 128) s_no[tid] = ld(node_opt, b * 128 + tid, isbf);
    __syncthreads();
    {   // q[u] = node_opt . Wq[u] + bq  (2 threads per output, 64 j each)
        float s = 0.f;
        const int j0 = half * 64;
        if (isbf) {
            #pragma unroll 8
            for (int j = 0; j < 64; ++j)
                s = fmaf(s_no[j0 + j], ld(in_proj_w, (size_t)u * 128 + j0 + j, 1), s);
        } else {
            const float* wr = (const float*)in_proj_w + (size_t)u * 128 + j0;
            #pragma unroll
            for (int i = 0; i < 16; ++i) {
                const float4 wv = *(const float4*)(wr + i * 4);
                s = fmaf(wv.x, s_no[j0+i*4+0], fmaf(wv.y, s_no[j0+i*4+1],
                    fmaf(wv.z, s_no[j0+i*4+2], fmaf(wv.w, s_no[j0+i*4+3], s))));
            }
        }
        sv2[half][u] = s;
    }
    __syncthreads();
    if (tid < 128) q[tid] = sv2[0][tid] + sv2[1][tid] + ld(in_proj_b, tid, isbf);
    __syncthreads();
    {   // qk[u] = sum_j q[j] * Wk[j][u]  (2 threads per output, 64 j each)
        float s = 0.f;
        const int j0 = half * 64;
        #pragma unroll 8
        for (int j = 0; j < 64; ++j)
            s = fmaf(q[j0 + j], ld(in_proj_w, (size_t)(128 + j0 + j) * 128 + u, isbf), s);
        sv2[half][u] = s;
    }
    if (tid == 0) {     // q . bk
        float s = 0.f;
        #pragma unroll 8
        for (int j = 0; j < 128; ++j)
            s = fmaf(q[j], ld(in_proj_b, 128 + j, isbf), s);
        red[10] = s;
    }
    __syncthreads();
    if (tid < 128) qk[tid] = sv2[0][tid] + sv2[1][tid];
    __syncthreads();
    {   // logit for path p = tid
        const float* lp = g_last + ((size_t)b * 256 + tid) * H_;
        const float s = dot128(lp, qk);
        logits[tid] = (s + red[10]) * 0.08838834764831845f;  // 1/sqrt(128)
    }
    __syncthreads();
    float v = logits[tid];
    #pragma unroll
    for (int off = 32; off > 0; off >>= 1) v = fmaxf(v, __shfl_xor(v, off, 64));
    if ((tid & 63) == 0) red[tid >> 6] = v;
    __syncthreads();
    if (tid == 0) red[8] = fmaxf(fmaxf(red[0], red[1]), fmaxf(red[2], red[3]));
    __syncthreads();
    const float e = __expf(logits[tid] - red[8]);
    float sum = e;
    #pragma unroll
    for (int off = 32; off > 0; off >>= 1) sum += __shfl_xor(sum, off, 64);
    if ((tid & 63) == 0) red[4 + (tid >> 6)] = sum;
    __syncthreads();
    if (tid == 0) red[9] = red[4] + red[5] + red[6] + red[7];
    __syncthreads();
    logits[tid] = e / red[9];
    __syncthreads();
    {   // sv[u] = sum_p attn[p] * last[b,p,u]  (2 threads per output)
        float s = 0.f;
        const float* lb = g_last + ((size_t)b * 256 + half * 128) * H_ + u;
        #pragma unroll 8
        for (int p = 0; p < 128; ++p)
            s = fmaf(logits[half * 128 + p], lb[(size_t)p * H_], s);
        sv2[half][u] = s;
    }
    __syncthreads();
    if (tid < 128) q[tid] = sv2[0][tid] + sv2[1][tid];   // reuse q[] as sv
    __syncthreads();
    if (tid < 128) {
        float s;
        if (isbf) {
            s = 0.f;
            #pragma unroll 8
            for (int j = 0; j < 128; ++j)
                s = fmaf(q[j], ld(in_proj_w, (size_t)(256 + tid) * 128 + j, 1), s);
        } else {
            s = dot128((const float*)in_proj_w + (size_t)(256 + tid) * 128, q);
        }
        ctx[tid] = s + ld(in_proj_b, 256 + tid, isbf);
    }
    __syncthreads();
    if (tid < 128) {
        float s;
        if (isbf) {
            s = 0.f;
            #pragma unroll 8
            for (int d = 0; d < 128; ++d)
                s = fmaf(ctx[d], ld(out_proj_w, (size_t)tid * 128 + d, 1), s);
        } else {
            s = dot128((const float*)out_proj_w + (size_t)tid * 128, ctx);
        }
        out[b * 128 + tid] = s + ld(out_proj_b, tid, isbf);
    }
}

// ---------------------------------------------------------------------------
extern "C" void kernel_launch(void* const* d_in, const int* in_sizes, int n_in,
                              void* d_out, int out_size, void* d_ws, size_t ws_size,
                              hipStream_t stream)
{
    const void* graph_embed = d_in[0];
    const void* node_opt    = d_in[1];
    const void* rel_embeds  = d_in[2];
    const void* W_ih        = d_in[3];
    const void* W_hh        = d_in[4];
    const void* b_ih        = d_in[5];
    const void* b_hh        = d_in[6];
    const void* in_proj_w   = d_in[7];
    const void* in_proj_b   = d_in[8];
    const void* out_proj_w  = d_in[9];
    const void* out_proj_b  = d_in[10];
    const int* node_idx  = (const int*)d_in[11];
    const int* rel_idx   = (const int*)d_in[12];
    const int* path_lens = (const int*)d_in[13];
    (void)d_ws; (void)ws_size; (void)in_sizes; (void)n_in; (void)out_size;

    hipLaunchKernelGGL(k_prep, dim3(657), dim3(512), 0, stream,
                       node_opt, node_idx, rel_embeds, W_ih, W_hh, b_ih, b_hh,
                       path_lens);
    hipLaunchKernelGGL(k_lstm, dim3(NPATH / NPB), dim3(512), 0, stream,
                       graph_embed, node_idx, rel_idx, path_lens);
    hipLaunchKernelGGL(k_attn, dim3(B_), dim3(256), 0, stream,
                       node_opt, in_proj_w, in_proj_b, out_proj_w, out_proj_b,
                       (float*)d_out);
}

// Round 12
// 191.587 us; speedup vs baseline: 1.7995x; 1.0579x over previous
//
#include <hip/hip_runtime.h>
#include <hip/hip_bf16.h>

// B=32, N=4096, P=256, L=16, DR=128, H=128, NUM_REL=400.
// Contract (verified r5-r8): float inputs f32, ints int32, output f32 [32][128].
// r9-r17 ladder: MFMA LSTM, rcp activations, lgkm-only barriers, NPB16 TLP
//   (60us), depth-2 x prefetch (55us).
// r18 lesson: Whh-in-LDS @1024thr = 169us (one barrier domain + VGPR 60).
// r19 lesson: launch_bounds(512,4) crushed VGPR to 64 -> total spill (193us).
// r20: rl-ahead prefetch w/ (512,2) = 53.6us k_lstm (VGPR 116, no spill).
// r21 (this round): attack the ~149us FIXED cost outside k_lstm (stable
//   across r9-r20; 2.8x k_lstm now). k_attn's first 4 serial phases
//   (s_no load, q proj, qk proj, q.bk) depend only on node_opt/in_proj_w —
//   moved into k_prep as 32 extra blocks (ride free: 657->689 blocks,
//   <3 blocks/CU). k_attn now starts at logits vs precomputed g_qk/g_qbk.
//   k_lstm UNTOUCHED (single-variable attribution; r19 lesson).
//   Prediction: total -> ~188-196us if those phases carried ~10-15us;
//   <5us move = k_attn front exonerated, fixed cost is harness/k_prep.

#define B_    32
#define N_    4096
#define L_    16
#define DR_   128
#define H_    128
#define G4_   512
#define AST2  264        // A row stride in bf16 elems (528B, 16B-aligned)
#define NPATH 8192
#define NPB   16

typedef unsigned short bfraw;
typedef short short8 __attribute__((ext_vector_type(8)));
typedef float f32x4 __attribute__((ext_vector_type(4)));

__device__ int   g_isbf16;
__device__ int   g_isi64;
__device__ __align__(16) bfraw g_Wcat[G4_ * 256];    // [n][k] bf16, 256KB
__device__ __align__(16) float g_relproj[400 * G4_]; // [400][128 units][4 gates] f32
__device__ float g_bias[G4_];
__device__ int   g_perm[NPATH];
__device__ float g_last[NPATH * H_];                 // f32 [8192][128]
__device__ __align__(16) float g_qk[B_ * H_];        // [32][128] Wk^T q
__device__ float g_qbk[B_];                          // q . bk

// lgkm-only barrier: LDS producer/consumer ordering without the vmcnt(0)
// drain __syncthreads carries. Global loads stay in flight across it.
#define BAR() asm volatile("s_waitcnt lgkmcnt(0)\n\ts_barrier" ::: "memory")

__device__ __forceinline__ float bfc(bfraw v) {
    return __uint_as_float(((unsigned)v) << 16);
}
__device__ __forceinline__ bfraw f2b(float f) {      // RNE f32->bf16
    unsigned u = __float_as_uint(f);
    return (bfraw)((u + 0x7FFFu + ((u >> 16) & 1u)) >> 16);
}
__device__ __forceinline__ unsigned pk2(float a, float b) {
    return (unsigned)f2b(a) | ((unsigned)f2b(b) << 16);
}
__device__ __forceinline__ float ld(const void* p, size_t i, int isbf) {
    return isbf ? bfc(((const bfraw*)p)[i]) : ((const float*)p)[i];
}
// v_rcp_f32-based activations (confirmed r11: VALUBusy 29->20%).
__device__ __forceinline__ float sigf(float x) {
    return __builtin_amdgcn_rcpf(1.0f + __expf(-x));
}
__device__ __forceinline__ float tanhfast(float x) {
    return 2.0f * sigf(2.0f * x) - 1.0f;
}

// dot of 128 contiguous f32 (global w) with 128 f32 in LDS
__device__ __forceinline__ float dot128(const float* __restrict__ w,
                                        const float* __restrict__ s) {
    float acc = 0.f;
    #pragma unroll
    for (int i = 0; i < 32; ++i) {
        const float4 wv = *(const float4*)(w + i * 4);
        acc = fmaf(wv.x, s[i*4+0], fmaf(wv.y, s[i*4+1],
              fmaf(wv.z, s[i*4+2], fmaf(wv.w, s[i*4+3], acc))));
    }
    return acc;
}

// ---------------------------------------------------------------------------
// Fused prep, grid 689 x 512 threads:
//   blocks 0..399   : rel_proj row r = blockIdx
//   blocks 400..655 : W repack chunk (256 x 512 elems)
//   block  656      : detect flags + bias + counting sort
//   blocks 657..688 : attention q/qk/q.bk precompute for batch b = blk-657
__global__ __launch_bounds__(512) void k_prep(
    const void* __restrict__ node_opt, const int* __restrict__ node_idx,
    const void* __restrict__ rel_embeds,
    const void* __restrict__ W_ih, const void* __restrict__ W_hh,
    const void* __restrict__ b_ih, const void* __restrict__ b_hh,
    const void* __restrict__ in_proj_w, const void* __restrict__ in_proj_b,
    const int* __restrict__ path_lens)
{
    __shared__ float relv[DR_];
    __shared__ float s_no2[128], s_q[128];
    __shared__ float sv4[4][128];
    __shared__ int s_big, s_nz, hist[16], cur[16];
    const int tid = threadIdx.x;
    const int blk = blockIdx.x;

    if (tid == 0) { s_big = 0; s_nz = 0; }
    __syncthreads();
    {
        const unsigned short* u = (const unsigned short*)node_opt;
        int big = 0;
        #pragma unroll
        for (int i = 0; i < 4; ++i) {
            const float v = fabsf(bfc(u[tid + i * 512]));
            big |= !(v < 1.0e3f);             // NaN-safe
        }
        if (big) s_big = 1;
        if (node_idx[2 * tid + 1] != 0) s_nz = 1;   // int width probe
    }
    __syncthreads();
    const int isbf = s_big ? 0 : 1;
    const int i64  = s_nz ? 0 : 1;

    if (blk < 400) {
        const int r = blk;
        if (tid < DR_) relv[tid] = ld(rel_embeds, (size_t)r * DR_ + tid, isbf);
        __syncthreads();
        const int n = tid;                     // 0..511, n = g*128+u
        float s;
        if (isbf) {
            s = 0.f;
            for (int d = 0; d < DR_; ++d)
                s = fmaf(relv[d], bfc(((const bfraw*)W_ih)[(size_t)n * 256 + 128 + d]), s);
        } else {
            s = dot128((const float*)W_ih + (size_t)n * 256 + 128, relv);
        }
        g_relproj[r * G4_ + ((n & 127) << 2) + (n >> 7)] = s;
    } else if (blk < 656) {
        const int idx = (blk - 400) * 512 + tid;   // 0..131071
        const int n = idx >> 8, k = idx & 255;
        const float v = (k < H_) ? ld(W_hh, (size_t)n * H_ + k, isbf)
                                 : ld(W_ih, (size_t)n * 256 + (k - H_), isbf);
        g_Wcat[n * 256 + k] = f2b(v);
    } else if (blk == 656) {
        if (tid == 0) { g_isbf16 = isbf; g_isi64 = i64; }
        g_bias[tid] = ld(b_ih, tid, isbf) + ld(b_hh, tid, isbf);
        if (tid < 16) hist[tid] = 0;
        __syncthreads();
        for (int p = tid; p < NPATH; p += 512) {
            const int len = i64 ? path_lens[2 * p] : path_lens[p];
            atomicAdd(&hist[len - 1], 1);
        }
        __syncthreads();
        if (tid == 0) {
            int off = 0;
            for (int b = 15; b >= 0; --b) { cur[b] = off; off += hist[b]; }
        }
        __syncthreads();
        for (int p = tid; p < NPATH; p += 512) {
            const int len = i64 ? path_lens[2 * p] : path_lens[p];
            const int pos = atomicAdd(&cur[len - 1], 1);
            g_perm[pos] = p;
        }
    } else {
        // ---- attention q/qk precompute for batch b (4 threads/output) ----
        const int b = blk - 657;
        const int u = tid & 127, quarter = tid >> 7;   // 0..3
        if (tid < 128) s_no2[tid] = ld(node_opt, b * 128 + tid, isbf);
        __syncthreads();
        {   // q[u] = node_opt . Wq[u]  (quarter j-ranges of 32)
            float s = 0.f;
            const int j0 = quarter * 32;
            if (isbf) {
                for (int j = 0; j < 32; ++j)
                    s = fmaf(s_no2[j0 + j], bfc(((const bfraw*)in_proj_w)[(size_t)u * 128 + j0 + j]), s);
            } else {
                const float* wr = (const float*)in_proj_w + (size_t)u * 128 + j0;
                #pragma unroll
                for (int i = 0; i < 8; ++i) {
                    const float4 wv = *(const float4*)(wr + i * 4);
                    s = fmaf(wv.x, s_no2[j0+i*4+0], fmaf(wv.y, s_no2[j0+i*4+1],
                        fmaf(wv.z, s_no2[j0+i*4+2], fmaf(wv.w, s_no2[j0+i*4+3], s))));
                }
            }
            sv4[quarter][u] = s;
        }
        __syncthreads();
        if (tid < 128)
            s_q[tid] = sv4[0][tid] + sv4[1][tid] + sv4[2][tid] + sv4[3][tid]
                     + ld(in_proj_b, tid, isbf);
        __syncthreads();
        {   // qk[u] = sum_j q[j] * Wk[j][u]
            float s = 0.f;
            const int j0 = quarter * 32;
            for (int j = 0; j < 32; ++j)
                s = fmaf(s_q[j0 + j], ld(in_proj_w, (size_t)(128 + j0 + j) * 128 + u, isbf), s);
            sv4[quarter][u] = s;
        }
        __syncthreads();
        if (tid < 128)
            g_qk[b * 128 + tid] = sv4[0][tid] + sv4[1][tid] + sv4[2][tid] + sv4[3][tid];
        if (tid == 128) {
            float s = 0.f;
            for (int j = 0; j < 128; ++j)
                s = fmaf(s_q[j], ld(in_proj_b, 128 + j, isbf), s);
            g_qbk[b] = s;
        }
    }
}

// ---------------------------------------------------------------------------
// MFMA LSTM (UNCHANGED from r20): 512 blocks x 512 threads, 16 paths/block,
// 2 blocks/CU, double-buffered A, one barrier/step, depth-2 x prefetch,
// one-step-ahead rl prefetch.
__global__ __launch_bounds__(512, 2) void k_lstm(
    const void* __restrict__ graph_embed,   // [32][4096][128] f32 (or bf16)
    const int*  __restrict__ node_idx,      // [8192][16]
    const int*  __restrict__ rel_idx,       // [8192][16]
    const int*  __restrict__ path_lens)     // [8192]
{
    __shared__ __align__(16) bfraw Abuf[2][NPB][AST2]; // [buf][path][ h | x ]
    __shared__ int s_pid[NPB], s_len[NPB];
    __shared__ int s_nid[NPB][L_], s_rid[NPB][L_];

    const int isbf = g_isbf16;
    const int i64  = g_isi64;
    const int tid  = threadIdx.x;

    if (tid < NPB) {
        const int pid = g_perm[blockIdx.x * NPB + tid];
        s_pid[tid] = pid;
        s_len[tid] = i64 ? path_lens[2 * pid] : path_lens[pid];
    }
    __syncthreads();
    if (tid < 256) {   // indices: 256 threads = 16 paths x 16 steps
        const int m = tid >> 4, t = tid & 15;
        const int idx = s_pid[m] * L_ + t;
        s_nid[m][t] = i64 ? node_idx[2 * idx] : node_idx[idx];
        s_rid[m][t] = i64 ? rel_idx[2 * idx]  : rel_idx[idx];
    }
    if (tid < 256) {   // zero h region of buffer 0 (k<128): 16 rows x 128 bf16
        const int m = tid >> 4, i0 = (tid & 15) * 8;
        *(uint4*)&Abuf[0][m][i0] = make_uint4(0, 0, 0, 0);
    }
    __syncthreads();

    int maxlen = 0;
    #pragma unroll
    for (int m = 0; m < NPB; ++m) maxlen = max(maxlen, s_len[m]);

    const int w    = tid >> 6;     // wave 0..7
    const int l    = tid & 63;
    const int quad = l >> 4;
    const int col  = l & 15;
    const int u0   = w * 16 + col; // owned unit

    // ---- resident W fragments: wreg[ck][g] = W[g*128+u0][ck*32+quad*8 ..+8] ----
    short8 wreg[8][4];
    float bq4[4];
    #pragma unroll
    for (int g = 0; g < 4; ++g) {
        bq4[g] = g_bias[g * 128 + u0];
        const bfraw* wrow = g_Wcat + (size_t)(g * 128 + u0) * 256 + quad * 8;
        #pragma unroll
        for (int ck = 0; ck < 8; ++ck)
            wreg[ck][g] = *(const short8*)(wrow + ck * 32);
    }

    // x-gather geometry: 32 threads/path, 4 elems (pi0) each.
    const int pm  = tid >> 5;          // path 0..15
    const int pi0 = (tid & 31) * 4;    // elem 0..124
    const size_t gbase = (size_t)(s_pid[pm] >> 8) * (size_t)(N_ * DR_);

    uint4 pnA, pnB;   // depth-2 x prefetch regs (f32: 4 floats; bf16: .x/.y)

    // ---- prologue: load + commit x(0) into buffer 0 (t=0 < len always) ----
    {
        const int nid = s_nid[pm][0];
        uint2 npk;
        if (isbf) {
            npk = *(const uint2*)((const bfraw*)graph_embed + gbase + (size_t)nid * DR_ + pi0);
        } else {
            const float* gp = (const float*)graph_embed + gbase + (size_t)nid * DR_ + pi0;
            const uint4 q = *(const uint4*)gp;
            const float* a = (const float*)&q;
            npk = make_uint2(pk2(a[0], a[1]), pk2(a[2], a[3]));
        }
        *(uint2*)&Abuf[0][pm][128 + pi0] = npk;
    }
    // issue x(1) -> pnA (committed at end of step 0)
    if (maxlen > 1) {
        const int nid = s_nid[pm][1];
        if (isbf) {
            const uint2 q = *(const uint2*)((const bfraw*)graph_embed + gbase + (size_t)nid * DR_ + pi0);
            pnA.x = q.x; pnA.y = q.y;
        } else {
            pnA = *(const uint4*)((const float*)graph_embed + gbase + (size_t)nid * DR_ + pi0);
        }
    }
    // issue rl(0) -> rlvA (consumed in step 0's gates, after MFMA)
    f32x4 rlvA[4];
    #pragma unroll
    for (int r = 0; r < 4; ++r) {
        const int m = quad * 4 + r;
        rlvA[r] = *(const f32x4*)(g_relproj + (size_t)s_rid[m][0] * G4_ + u0 * 4);
    }
    __syncthreads();                       // x(0) + h(-1)=0 visible

    float c[4];
    #pragma unroll
    for (int r = 0; r < 4; ++r) c[r] = 0.f;

    bfraw (*Ar)[AST2] = Abuf[0];   // read buffer  (h(t-1), x(t))
    bfraw (*Aw)[AST2] = Abuf[1];   // write buffer (h(t), x(t+1))

    for (int t = 0; t < maxlen; ++t) {
        const bool more = (t + 1 < maxlen);   // block-uniform

        // [A] issue x(t+2) -> pnB (window ~2 steps covers miss latency).
        if (t + 2 < maxlen) {
            const int nid = s_nid[pm][t + 2];
            if (isbf) {
                const uint2 q = *(const uint2*)((const bfraw*)graph_embed + gbase + (size_t)nid * DR_ + pi0);
                pnB.x = q.x; pnB.y = q.y;
            } else {
                pnB = *(const uint4*)((const float*)graph_embed + gbase + (size_t)nid * DR_ + pi0);
            }
        }

        // [B] MFMA K-loop: A[cur] from LDS, W from registers (M=16 tile)
        f32x4 acc[4];
        #pragma unroll
        for (int g = 0; g < 4; ++g) {
            const float b = bq4[g];
            acc[g][0] = b; acc[g][1] = b; acc[g][2] = b; acc[g][3] = b;
        }
        #pragma unroll
        for (int ck = 0; ck < 8; ++ck) {
            const short8 a0 = *(const short8*)&Ar[col][ck * 32 + quad * 8];
            #pragma unroll
            for (int g = 0; g < 4; ++g)
                acc[g] = __builtin_amdgcn_mfma_f32_16x16x32_bf16(a0, wreg[ck][g], acc[g], 0, 0, 0);
        }
        // (no sched fence: gates may interleave with MFMA drain; rl loads
        // for this step were issued LAST step, so nothing to pin here.)

        // [C] gates + cell update; rlvA was loaded one step ago (latency
        // covered by barrier + MFMA). h(t) goes to the WRITE buffer.
        #pragma unroll
        for (int r = 0; r < 4; ++r) {
            const int m = quad * 4 + r;
            const float relm = (t < s_len[m] - 1) ? 1.0f : 0.0f;
            const float ig = sigf(acc[0][r] + relm * rlvA[r][0]);
            const float fg = sigf(acc[1][r] + relm * rlvA[r][1]);
            const float gg = tanhfast(acc[2][r] + relm * rlvA[r][2]);
            const float og = sigf(acc[3][r] + relm * rlvA[r][3]);
            const float cc = fg * c[r] + ig * gg;
            c[r] = cc;
            const float h = og * tanhfast(cc);
            Aw[m][u0] = f2b(h);
            if (t == s_len[m] - 1)
                g_last[(size_t)s_pid[m] * H_ + u0] = h;
        }

        // [D] commit pnA = x(t+1) into the WRITE buffer (masked per-path);
        // rotate the x prefetch pipe.
        if (more) {
            uint2 npk = make_uint2(0, 0);
            if (t + 1 < s_len[pm]) {
                if (isbf) npk = make_uint2(pnA.x, pnA.y);
                else {
                    const float* a = (const float*)&pnA;
                    npk = make_uint2(pk2(a[0], a[1]), pk2(a[2], a[3]));
                }
            }
            *(uint2*)&Aw[pm][128 + pi0] = npk;
            pnA = pnB;
        }

        // [E] issue rl(t+1) directly into rlvA (old value dead after gates).
        if (more) {
            #pragma unroll
            for (int r = 0; r < 4; ++r) {
                const int m = quad * 4 + r;
                rlvA[r] = *(const f32x4*)(g_relproj + (size_t)s_rid[m][t + 1] * G4_ + u0 * 4);
            }
        }

        // [F] single barrier: my A[cur] reads retired (own lgkm drain); all
        // waves' A[nxt] writes visible for step t+1. Buffers swap roles.
        BAR();
        bfraw (*tmp)[AST2] = Ar; Ar = Aw; Aw = tmp;
    }
}

// ---------------------------------------------------------------------------
// Attention epilogue v2: starts at logits using precomputed g_qk/g_qbk.
// One block (256 threads) per batch element; 6 phases (was ~10).
__global__ __launch_bounds__(256) void k_attn(
    const void* __restrict__ in_proj_w,   // [384][128] (Wv rows 256..383)
    const void* __restrict__ in_proj_b,   // [384]
    const void* __restrict__ out_proj_w,  // [128][128]
    const void* __restrict__ out_proj_b,  // [128]
    float* __restrict__ out)              // [32][128] f32
{
    const int isbf = g_isbf16;
    const int b = blockIdx.x, tid = threadIdx.x;
    __shared__ __align__(16) float sv2[2][128], svv[128], ctx[128];
    __shared__ float logits[256];
    __shared__ float red[12];

    const int u    = tid & 127;      // output index for split phases
    const int half = tid >> 7;       // 0/1

    {   // logits: last_p . qk + qbk (both operands L2-broadcast)
        const float* lp = g_last + ((size_t)b * 256 + tid) * H_;
        const float* qk = g_qk + b * 128;
        float s = 0.f;
        #pragma unroll
        for (int i = 0; i < 32; ++i) {
            const float4 a = *(const float4*)(lp + i * 4);
            const float4 wv = *(const float4*)(qk + i * 4);
            s = fmaf(a.x, wv.x, fmaf(a.y, wv.y, fmaf(a.z, wv.z, fmaf(a.w, wv.w, s))));
        }
        logits[tid] = (s + g_qbk[b]) * 0.08838834764831845f;  // 1/sqrt(128)
    }
    __syncthreads();
    float v = logits[tid];
    #pragma unroll
    for (int off = 32; off > 0; off >>= 1) v = fmaxf(v, __shfl_xor(v, off, 64));
    if ((tid & 63) == 0) red[tid >> 6] = v;
    __syncthreads();
    if (tid == 0) red[8] = fmaxf(fmaxf(red[0], red[1]), fmaxf(red[2], red[3]));
    __syncthreads();
    const float e = __expf(logits[tid] - red[8]);
    float sum = e;
    #pragma unroll
    for (int off = 32; off > 0; off >>= 1) sum += __shfl_xor(sum, off, 64);
    if ((tid & 63) == 0) red[4 + (tid >> 6)] = sum;
    __syncthreads();
    if (tid == 0) red[9] = red[4] + red[5] + red[6] + red[7];
    __syncthreads();
    logits[tid] = e / red[9];
    __syncthreads();
    {   // sv[u] = sum_p attn[p] * last[b,p,u]  (2 threads per output)
        float s = 0.f;
        const float* lb = g_last + ((size_t)b * 256 + half * 128) * H_ + u;
        #pragma unroll 8
        for (int p = 0; p < 128; ++p)
            s = fmaf(logits[half * 128 + p], lb[(size_t)p * H_], s);
        sv2[half][u] = s;
    }
    __syncthreads();
    if (tid < 128) svv[tid] = sv2[0][tid] + sv2[1][tid];
    __syncthreads();
    if (tid < 128) {
        float s;
        if (isbf) {
            s = 0.f;
            #pragma unroll 8
            for (int j = 0; j < 128; ++j)
                s = fmaf(svv[j], ld(in_proj_w, (size_t)(256 + tid) * 128 + j, 1), s);
        } else {
            s = dot128((const float*)in_proj_w + (size_t)(256 + tid) * 128, svv);
        }
        ctx[tid] = s + ld(in_proj_b, 256 + tid, isbf);
    }
    __syncthreads();
    if (tid < 128) {
        float s;
        if (isbf) {
            s = 0.f;
            #pragma unroll 8
            for (int d = 0; d < 128; ++d)
                s = fmaf(ctx[d], ld(out_proj_w, (size_t)tid * 128 + d, 1), s);
        } else {
            s = dot128((const float*)out_proj_w + (size_t)tid * 128, ctx);
        }
        out[b * 128 + tid] = s + ld(out_proj_b, tid, isbf);
    }
}

// ---------------------------------------------------------------------------
extern "C" void kernel_launch(void* const* d_in, const int* in_sizes, int n_in,
                              void* d_out, int out_size, void* d_ws, size_t ws_size,
                              hipStream_t stream)
{
    const void* graph_embed = d_in[0];
    const void* node_opt    = d_in[1];
    const void* rel_embeds  = d_in[2];
    const void* W_ih        = d_in[3];
    const void* W_hh        = d_in[4];
    const void* b_ih        = d_in[5];
    const void* b_hh        = d_in[6];
    const void* in_proj_w   = d_in[7];
    const void* in_proj_b   = d_in[8];
    const void* out_proj_w  = d_in[9];
    const void* out_proj_b  = d_in[10];
    const int* node_idx  = (const int*)d_in[11];
    const int* rel_idx   = (const int*)d_in[12];
    const int* path_lens = (const int*)d_in[13];
    (void)d_ws; (void)ws_size; (void)in_sizes; (void)n_in; (void)out_size;

    hipLaunchKernelGGL(k_prep, dim3(689), dim3(512), 0, stream,
                       node_opt, node_idx, rel_embeds, W_ih, W_hh, b_ih, b_hh,
                       in_proj_w, in_proj_b, path_lens);
    hipLaunchKernelGGL(k_lstm, dim3(NPATH / NPB), dim3(512), 0, stream,
                       graph_embed, node_idx, rel_idx, path_lens);
    hipLaunchKernelGGL(k_attn, dim3(B_), dim3(256), 0, stream,
                       in_proj_w, in_proj_b, out_proj_w, out_proj_b,
                       (float*)d_out);
}